// Round 8
// baseline (980.744 us; speedup 1.0000x reference)
//
#include <hip/hip_runtime.h>
#include <hip/hip_bf16.h>

// R-GCN (2-layer) + mean-pool + linear + softmax, MI355X.
// v2: two-phase edge flow. Round-5 rocprof showed edge kernels bound by
// device-scope fp32 atomic RMW (WRITE_SIZE == atomic payload 400 MB @ 2 TB/s,
// VALUBusy 53%). Phase A: rel-sorted chunks, W[r] in VGPRs, per-edge msg
// written with plain sequential stores. Phase B: dst-CSR gather-reduce
// (coalesced 256B reads) fused with self-loop + bias + relu (+ mean-pool).

#define IN_DIM 32
#define HID 64
#define NREL 16
#define NCLS 8
#define CHUNK 2048   // scan chunk: 256 threads x 8

__device__ __forceinline__ int rfl(int v) { return __builtin_amdgcn_readfirstlane(v); }
__device__ __forceinline__ int rl(int v, int l) { return __builtin_amdgcn_readlane(v, l); }

// ---------------- histograms ----------------

__global__ void hist_rel(const int* __restrict__ rel, int* __restrict__ hist, int E) {
  __shared__ int lh[NREL];
  int tid = threadIdx.x;
  if (tid < NREL) lh[tid] = 0;
  __syncthreads();
  for (int e = blockIdx.x * blockDim.x + tid; e < E; e += gridDim.x * blockDim.x)
    atomicAdd(&lh[rel[e]], 1);
  __syncthreads();
  if (tid < NREL && lh[tid] > 0) atomicAdd(&hist[tid], lh[tid]);
}

__global__ void hist_dst_k(const int* __restrict__ dst, int* __restrict__ histd, int E) {
  for (int e = blockIdx.x * blockDim.x + threadIdx.x; e < E; e += gridDim.x * blockDim.x)
    atomicAdd(&histd[dst[e]], 1);
}

__global__ void scan16(const int* __restrict__ hist, int* __restrict__ offs,
                       int* __restrict__ fillrel) {
  if (threadIdx.x == 0) {
    int o = 0;
    for (int r = 0; r < NREL; ++r) {
      offs[r] = o;
      fillrel[r] = o;
      o += (hist[r] + 63) & ~63;   // 64-aligned buckets -> chunk has uniform rel
    }
    offs[NREL] = o;
  }
}

// fill ONLY bucket gaps (and the region past the last bucket) with src=0
__global__ void pad_gaps(const int* __restrict__ hist, const int* __restrict__ offs,
                         int* __restrict__ ssrc, int Epad) {
  int r = blockIdx.x;                       // 0..NREL (17 blocks)
  int lo = (r < NREL) ? offs[r] + hist[r] : offs[NREL];
  int hi = (r < NREL) ? offs[r + 1] : Epad;
  for (int i = lo + threadIdx.x; i < hi; i += blockDim.x) ssrc[i] = 0;
}

// ---------------- exclusive scan over histd[N] -> rowptr/filldst ----------------

__global__ void scan1_k(const int* __restrict__ histd, int* __restrict__ csum, int N) {
  __shared__ int red[256];
  int t = threadIdx.x;
  int base = blockIdx.x * CHUNK + t * 8;
  int s = 0;
#pragma unroll
  for (int i = 0; i < 8; ++i) { int idx = base + i; s += (idx < N) ? histd[idx] : 0; }
  red[t] = s; __syncthreads();
  for (int off = 128; off > 0; off >>= 1) {
    if (t < off) red[t] += red[t + off];
    __syncthreads();
  }
  if (t == 0) csum[blockIdx.x] = red[0];
}

__global__ void scan2_k(const int* __restrict__ csum, int* __restrict__ cbase,
                        int* __restrict__ rowptr, int nchunks, int N) {
  if (threadIdx.x == 0) {
    int run = 0;
    for (int c = 0; c < nchunks; ++c) { cbase[c] = run; run += csum[c]; }
    rowptr[N] = run;   // == E
  }
}

__global__ void scan3_k(const int* __restrict__ histd, const int* __restrict__ cbase,
                        int* __restrict__ rowptr, int* __restrict__ filldst, int N) {
  __shared__ int ts[256];
  int t = threadIdx.x;
  int base = blockIdx.x * CHUNK + t * 8;
  int v[8]; int s = 0;
#pragma unroll
  for (int i = 0; i < 8; ++i) { int idx = base + i; int x = (idx < N) ? histd[idx] : 0; v[i] = x; s += x; }
  ts[t] = s; __syncthreads();
  int x = s;
  for (int off = 1; off < 256; off <<= 1) {
    int y = (t >= off) ? ts[t - off] : 0;
    __syncthreads();
    x += y; ts[t] = x;
    __syncthreads();
  }
  int run = cbase[blockIdx.x] + x - s;      // exclusive prefix for this thread
#pragma unroll
  for (int i = 0; i < 8; ++i) {
    int idx = base + i;
    if (idx < N) { rowptr[idx] = run; filldst[idx] = run; run += v[i]; }
  }
}

// ---------------- scatter: rel-sorted ssrc + dst-CSR eidx ----------------

__global__ void scatter_rel2(const int* __restrict__ rel, const int* __restrict__ src,
                             const int* __restrict__ dst, int* __restrict__ fillrel,
                             int* __restrict__ filldst, int* __restrict__ ssrc,
                             int* __restrict__ eidx, int E) {
  __shared__ int lc[NREL];
  __shared__ int lbase[NREL];
  int tid = threadIdx.x;
  if (tid < NREL) lc[tid] = 0;
  __syncthreads();
  int e = blockIdx.x * blockDim.x + tid;
  int r = 0, lo = 0;
  bool valid = (e < E);
  if (valid) { r = rel[e]; lo = atomicAdd(&lc[r], 1); }
  __syncthreads();
  if (tid < NREL && lc[tid] > 0) lbase[tid] = atomicAdd(&fillrel[tid], lc[tid]);
  __syncthreads();
  if (valid) {
    int p = lbase[r] + lo;                 // rel-sorted slot
    ssrc[p] = src[e];
    int q = atomicAdd(&filldst[dst[e]], 1);
    eidx[q] = p;                           // dst-CSR -> rel-sorted slot
  }
}

// ---------------- phase A: per-edge transform, sequential msg store ----------------

template <int IN>
__global__ void edge_msg(const float* __restrict__ hin, const int* __restrict__ ssrc,
                         const float* __restrict__ W, const int* __restrict__ offs,
                         float* __restrict__ msg, int maxchunks) {
  const int lane = threadIdx.x & 63;
  int wid = rfl((int)(blockIdx.x * (blockDim.x >> 6) + (threadIdx.x >> 6)));
  if (wid >= maxchunks) return;
  const int base = wid * 64;

  int r = 0;
#pragma unroll
  for (int k = 1; k < NREL; ++k) r += (base >= offs[k]) ? 1 : 0;

  const float* Wr = W + (size_t)r * (IN * HID);
  float w[IN];
#pragma unroll
  for (int i = 0; i < IN; ++i) w[i] = Wr[i * HID + lane];

  const int mys = ssrc[base + lane];

#pragma unroll 4
  for (int k = 0; k < 64; ++k) {
    const int s = rl(mys, k);
    const float4* __restrict__ row = (const float4*)(hin + (size_t)s * IN);
    float a0 = 0.f, a1 = 0.f, a2 = 0.f, a3 = 0.f;
#pragma unroll
    for (int i = 0; i < IN / 4; ++i) {
      float4 hv = row[i];
      a0 = fmaf(hv.x, w[4 * i + 0], a0);
      a1 = fmaf(hv.y, w[4 * i + 1], a1);
      a2 = fmaf(hv.z, w[4 * i + 2], a2);
      a3 = fmaf(hv.w, w[4 * i + 3], a3);
    }
    msg[(size_t)(base + k) * HID + lane] = (a0 + a1) + (a2 + a3);   // plain store
  }
}

// ---------------- phase B: dst-CSR gather + selfloop + bias + relu (+pool) ----------------

template <int IN, bool POOL>
__global__ void gather_fin(const float* __restrict__ msg, const int* __restrict__ eidx,
                           const int* __restrict__ rowptr, const float* __restrict__ hprev,
                           const float* __restrict__ Wl, const float* __restrict__ b,
                           const int* __restrict__ n2g, float* __restrict__ out,
                           float* __restrict__ pooled, float* __restrict__ cnt, int N) {
  const int lane = threadIdx.x & 63;
  int wid = rfl((int)(blockIdx.x * (blockDim.x >> 6) + (threadIdx.x >> 6)));
  int nw = gridDim.x * (blockDim.x >> 6);
  int per = (N + nw - 1) / nw;
  int n0 = wid * per, n1 = min(N, n0 + per);
  if (n0 >= n1) return;

  float wl[IN];
#pragma unroll
  for (int i = 0; i < IN; ++i) wl[i] = Wl[i * HID + lane];
  float bv = b[lane];

  float psum = 0.f, pcnt = 0.f;
  int pg = -1;
  for (int n = n0; n < n1; ++n) {
    int j0 = rowptr[n], j1 = rowptr[n + 1];
    float a0 = 0.f, a1 = 0.f, a2 = 0.f, a3 = 0.f;
    int j = j0;
    while (j < j1) {
      int c = min(j1 - j, 64);
      int vidx = (lane < c) ? eidx[j + lane] : 0;   // coalesced batch of indices
      int k = 0;
      for (; k + 3 < c; k += 4) {
        int i0 = rl(vidx, k), i1 = rl(vidx, k + 1), i2 = rl(vidx, k + 2), i3 = rl(vidx, k + 3);
        a0 += msg[(size_t)i0 * HID + lane];
        a1 += msg[(size_t)i1 * HID + lane];
        a2 += msg[(size_t)i2 * HID + lane];
        a3 += msg[(size_t)i3 * HID + lane];
      }
      for (; k < c; ++k) a0 += msg[(size_t)rl(vidx, k) * HID + lane];
      j += c;
    }
    const float4* __restrict__ row = (const float4*)(hprev + (size_t)n * IN);
    float s0 = 0.f, s1 = 0.f, s2 = 0.f, s3 = 0.f;
#pragma unroll
    for (int i = 0; i < IN / 4; ++i) {
      float4 hv = row[i];
      s0 = fmaf(hv.x, wl[4 * i + 0], s0);
      s1 = fmaf(hv.y, wl[4 * i + 1], s1);
      s2 = fmaf(hv.z, wl[4 * i + 2], s2);
      s3 = fmaf(hv.w, wl[4 * i + 3], s3);
    }
    float v = (a0 + a1) + (a2 + a3) + (s0 + s1) + (s2 + s3) + bv;
    v = fmaxf(v, 0.f);
    if (POOL) {
      int g = rfl(n2g[n]);
      if (g != pg) {
        if (pg >= 0) {
          atomicAdd(&pooled[(size_t)pg * HID + lane], psum);
          if (lane == 0) atomicAdd(&cnt[pg], pcnt);
        }
        pg = g; psum = 0.f; pcnt = 0.f;
      }
      psum += v; pcnt += 1.f;
    } else {
      out[(size_t)n * HID + lane] = v;
    }
  }
  if (POOL && pg >= 0) {
    atomicAdd(&pooled[(size_t)pg * HID + lane], psum);
    if (lane == 0) atomicAdd(&cnt[pg], pcnt);
  }
}

// ---------------- classifier + softmax ----------------

__global__ void classifier(const float* __restrict__ pooled, const float* __restrict__ cnt,
                           const float* __restrict__ Wc, const float* __restrict__ bc,
                           float* __restrict__ out, int B) {
  int g = blockIdx.x * blockDim.x + threadIdx.x;
  if (g >= B) return;
  float c = fmaxf(cnt[g], 1.f);
  float lg[NCLS];
#pragma unroll
  for (int cc = 0; cc < NCLS; ++cc) lg[cc] = bc[cc];
  for (int k = 0; k < HID; ++k) {
    float hg = pooled[(size_t)g * HID + k] / c;
#pragma unroll
    for (int cc = 0; cc < NCLS; ++cc) lg[cc] = fmaf(hg, Wc[k * NCLS + cc], lg[cc]);
  }
  float m = lg[0];
#pragma unroll
  for (int cc = 1; cc < NCLS; ++cc) m = fmaxf(m, lg[cc]);
  float s = 0.f;
#pragma unroll
  for (int cc = 0; cc < NCLS; ++cc) { lg[cc] = __expf(lg[cc] - m); s += lg[cc]; }
  float inv = 1.f / s;
#pragma unroll
  for (int cc = 0; cc < NCLS; ++cc) out[(size_t)g * NCLS + cc] = lg[cc] * inv;
}

// ---------------- fallback (round-5 measured-correct atomic path) ----------------

__global__ void fill_pad(int* __restrict__ ssrc, int* __restrict__ sdst, int Epad, int N) {
  int i = blockIdx.x * blockDim.x + threadIdx.x;
  if (i < Epad) { ssrc[i] = 0; sdst[i] = N; }
}

__global__ void scatter_rel(const int* __restrict__ rel, const int* __restrict__ src,
                            const int* __restrict__ dst, int* __restrict__ fill,
                            int* __restrict__ ssrc, int* __restrict__ sdst, int E) {
  __shared__ int lc[NREL];
  __shared__ int lbase[NREL];
  int tid = threadIdx.x;
  if (tid < NREL) lc[tid] = 0;
  __syncthreads();
  int e = blockIdx.x * blockDim.x + tid;
  int r = 0, lo = 0;
  bool valid = (e < E);
  if (valid) { r = rel[e]; lo = atomicAdd(&lc[r], 1); }
  __syncthreads();
  if (tid < NREL && lc[tid] > 0) lbase[tid] = atomicAdd(&fill[tid], lc[tid]);
  __syncthreads();
  if (valid) { int p = lbase[r] + lo; ssrc[p] = src[e]; sdst[p] = dst[e]; }
}

template <int IN>
__global__ void edge_layer(const float* __restrict__ hin, const int* __restrict__ ssrc,
                           const int* __restrict__ sdst, const float* __restrict__ W,
                           const int* __restrict__ offs, float* __restrict__ agg,
                           int maxchunks) {
  const int lane = threadIdx.x & 63;
  int wid = rfl((int)(blockIdx.x * (blockDim.x >> 6) + (threadIdx.x >> 6)));
  if (wid >= maxchunks) return;
  const int base = wid * 64;
  int r = 0;
#pragma unroll
  for (int k = 1; k < NREL; ++k) r += (base >= offs[k]) ? 1 : 0;
  const float* Wr = W + (size_t)r * (IN * HID);
  float w[IN];
#pragma unroll
  for (int i = 0; i < IN; ++i) w[i] = Wr[i * HID + lane];
  const int myd = sdst[base + lane];
  const int mys = ssrc[base + lane];
#pragma unroll 4
  for (int k = 0; k < 64; ++k) {
    const int d = rl(myd, k);
    const int s = rl(mys, k);
    const float4* __restrict__ row = (const float4*)(hin + (size_t)s * IN);
    float a0 = 0.f, a1 = 0.f, a2 = 0.f, a3 = 0.f;
#pragma unroll
    for (int i = 0; i < IN / 4; ++i) {
      float4 hv = row[i];
      a0 = fmaf(hv.x, w[4 * i + 0], a0);
      a1 = fmaf(hv.y, w[4 * i + 1], a1);
      a2 = fmaf(hv.z, w[4 * i + 2], a2);
      a3 = fmaf(hv.w, w[4 * i + 3], a3);
    }
    atomicAdd(&agg[(size_t)d * HID + lane], (a0 + a1) + (a2 + a3));
  }
}

__global__ void finalize1(const float* __restrict__ agg, const float* __restrict__ h,
                          const float* __restrict__ Wl, const float* __restrict__ b,
                          float* __restrict__ h1, int N) {
  const int lane = threadIdx.x & 63;
  int wid = rfl((int)(blockIdx.x * (blockDim.x >> 6) + (threadIdx.x >> 6)));
  int nw = gridDim.x * (blockDim.x >> 6);
  float wl[IN_DIM];
#pragma unroll
  for (int i = 0; i < IN_DIM; ++i) wl[i] = Wl[i * HID + lane];
  float bv = b[lane];
  for (int n = wid; n < N; n += nw) {
    const float4* __restrict__ row = (const float4*)(h + (size_t)n * IN_DIM);
    float a0 = 0.f, a1 = 0.f, a2 = 0.f, a3 = 0.f;
#pragma unroll
    for (int i = 0; i < IN_DIM / 4; ++i) {
      float4 hv = row[i];
      a0 = fmaf(hv.x, wl[4 * i + 0], a0);
      a1 = fmaf(hv.y, wl[4 * i + 1], a1);
      a2 = fmaf(hv.z, wl[4 * i + 2], a2);
      a3 = fmaf(hv.w, wl[4 * i + 3], a3);
    }
    float v = agg[(size_t)n * HID + lane] + (a0 + a1) + (a2 + a3) + bv;
    h1[(size_t)n * HID + lane] = fmaxf(v, 0.f);
  }
}

__global__ void finalize2_pool(const float* __restrict__ agg, const float* __restrict__ h1,
                               const float* __restrict__ Wl, const float* __restrict__ b,
                               const int* __restrict__ n2g,
                               float* __restrict__ pooled, float* __restrict__ cnt, int N) {
  const int lane = threadIdx.x & 63;
  int wid = rfl((int)(blockIdx.x * (blockDim.x >> 6) + (threadIdx.x >> 6)));
  int nw = gridDim.x * (blockDim.x >> 6);
  int per = (N + nw - 1) / nw;
  int n0 = wid * per, n1 = min(N, n0 + per);
  if (n0 >= n1) return;
  float wl[HID];
#pragma unroll
  for (int i = 0; i < HID; ++i) wl[i] = Wl[i * HID + lane];
  float bv = b[lane];
  float psum = 0.f, pcnt = 0.f;
  int pg = -1;
  for (int n = n0; n < n1; ++n) {
    const float4* __restrict__ row = (const float4*)(h1 + (size_t)n * HID);
    float a0 = 0.f, a1 = 0.f, a2 = 0.f, a3 = 0.f;
#pragma unroll
    for (int i = 0; i < HID / 4; ++i) {
      float4 hv = row[i];
      a0 = fmaf(hv.x, wl[4 * i + 0], a0);
      a1 = fmaf(hv.y, wl[4 * i + 1], a1);
      a2 = fmaf(hv.z, wl[4 * i + 2], a2);
      a3 = fmaf(hv.w, wl[4 * i + 3], a3);
    }
    float v = agg[(size_t)n * HID + lane] + (a0 + a1) + (a2 + a3) + bv;
    v = fmaxf(v, 0.f);
    int g = rfl(n2g[n]);
    if (g != pg) {
      if (pg >= 0) {
        atomicAdd(&pooled[(size_t)pg * HID + lane], psum);
        if (lane == 0) atomicAdd(&cnt[pg], pcnt);
      }
      pg = g; psum = 0.f; pcnt = 0.f;
    }
    psum += v; pcnt += 1.f;
  }
  if (pg >= 0) {
    atomicAdd(&pooled[(size_t)pg * HID + lane], psum);
    if (lane == 0) atomicAdd(&cnt[pg], pcnt);
  }
}

// ---------------- launch ----------------

extern "C" void kernel_launch(void* const* d_in, const int* in_sizes, int n_in,
                              void* d_out, int out_size, void* d_ws, size_t ws_size,
                              hipStream_t stream) {
  const float* h   = (const float*)d_in[0];
  const int* src   = (const int*)d_in[1];
  const int* dst   = (const int*)d_in[2];
  const int* rel   = (const int*)d_in[3];
  const int* n2g   = (const int*)d_in[4];
  const float* W1  = (const float*)d_in[5];
  const float* Wl1 = (const float*)d_in[6];
  const float* b1  = (const float*)d_in[7];
  const float* W2  = (const float*)d_in[8];
  const float* Wl2 = (const float*)d_in[9];
  const float* b2  = (const float*)d_in[10];
  const float* Wc  = (const float*)d_in[11];
  const float* bc  = (const float*)d_in[12];

  const int N = in_sizes[0] / IN_DIM;
  const int E = in_sizes[1];
  const int B = out_size / NCLS;

  const int maxchunks = (E + 63) / 64 + NREL;
  const int Epad = maxchunks * 64;
  const int nchunks = (N + CHUNK - 1) / CHUNK;
  const int eblocks = (maxchunks + 3) / 4;

  // ---- new-path workspace layout (elements of 4B) ----
  // h1 | msg | ssrc | eidx | rowptr(N+1) | filldst(N) | histd(N) | csum | cbase
  // | hist(16) | offs(17) | fillrel(16) | pooled(B*HID) | cnt(B)
  size_t need_elems = (size_t)N * HID + (size_t)Epad * HID + (size_t)Epad * 2 +
                      (size_t)(N + 1) + N + N + nchunks * 2 + 49 +
                      (size_t)B * HID + B + 64;
  if (ws_size >= need_elems * 4) {
    float* h1     = (float*)d_ws;
    float* msg    = h1 + (size_t)N * HID;
    int*   ssrc   = (int*)(msg + (size_t)Epad * HID);
    int*   eidx   = ssrc + Epad;
    int*   rowptr = eidx + Epad;
    int*   filldst= rowptr + (N + 1);
    int*   histd  = filldst + N;
    int*   csum   = histd + N;
    int*   cbase  = csum + nchunks;
    int*   hist   = cbase + nchunks;
    int*   offs   = hist + NREL;
    int*   fillrel= offs + NREL + 1;
    float* pooled = (float*)(fillrel + NREL);
    float* cnt    = pooled + (size_t)B * HID;

    hipMemsetAsync(hist, 0, NREL * sizeof(int), stream);
    hipMemsetAsync(histd, 0, (size_t)N * sizeof(int), stream);
    hipMemsetAsync(pooled, 0, (size_t)(B * HID + B) * sizeof(float), stream);

    hist_rel<<<1024, 256, 0, stream>>>(rel, hist, E);
    hist_dst_k<<<1024, 256, 0, stream>>>(dst, histd, E);
    scan16<<<1, 64, 0, stream>>>(hist, offs, fillrel);
    scan1_k<<<nchunks, 256, 0, stream>>>(histd, csum, N);
    scan2_k<<<1, 64, 0, stream>>>(csum, cbase, rowptr, nchunks, N);
    scan3_k<<<nchunks, 256, 0, stream>>>(histd, cbase, rowptr, filldst, N);
    pad_gaps<<<NREL + 1, 64, 0, stream>>>(hist, offs, ssrc, Epad);
    scatter_rel2<<<(E + 255) / 256, 256, 0, stream>>>(rel, src, dst, fillrel, filldst,
                                                      ssrc, eidx, E);

    edge_msg<IN_DIM><<<eblocks, 256, 0, stream>>>(h, ssrc, W1, offs, msg, maxchunks);
    gather_fin<IN_DIM, false><<<1024, 256, 0, stream>>>(msg, eidx, rowptr, h, Wl1, b1,
                                                        nullptr, h1, nullptr, nullptr, N);
    edge_msg<HID><<<eblocks, 256, 0, stream>>>(h1, ssrc, W2, offs, msg, maxchunks);
    gather_fin<HID, true><<<1024, 256, 0, stream>>>(msg, eidx, rowptr, h1, Wl2, b2,
                                                    n2g, nullptr, pooled, cnt, N);
    classifier<<<(B + 127) / 128, 128, 0, stream>>>(pooled, cnt, Wc, bc, (float*)d_out, B);
    return;
  }

  // ---- fallback: round-5 measured-correct atomic path ----
  float* agg    = (float*)d_ws;
  float* h1     = agg + (size_t)(N + 1) * HID;
  int*   ssrc   = (int*)(h1 + (size_t)N * HID);
  int*   sdst   = ssrc + Epad;
  int*   hist   = sdst + Epad;
  int*   offs   = hist + NREL;
  int*   fill   = offs + NREL + 1;
  float* pooled = (float*)(fill + NREL);
  float* cnt    = pooled + (size_t)B * HID;

  hipMemsetAsync(hist, 0, NREL * sizeof(int), stream);
  hipMemsetAsync(pooled, 0, (size_t)(B * HID + B) * sizeof(float), stream);
  fill_pad<<<(Epad + 255) / 256, 256, 0, stream>>>(ssrc, sdst, Epad, N);
  hist_rel<<<1024, 256, 0, stream>>>(rel, hist, E);
  scan16<<<1, 64, 0, stream>>>(hist, offs, fill);
  scatter_rel<<<(E + 255) / 256, 256, 0, stream>>>(rel, src, dst, fill, ssrc, sdst, E);
  hipMemsetAsync(agg, 0, (size_t)(N + 1) * HID * sizeof(float), stream);
  edge_layer<IN_DIM><<<eblocks, 256, 0, stream>>>(h, ssrc, sdst, W1, offs, agg, maxchunks);
  finalize1<<<2048, 256, 0, stream>>>(agg, h, Wl1, b1, h1, N);
  hipMemsetAsync(agg, 0, (size_t)(N + 1) * HID * sizeof(float), stream);
  edge_layer<HID><<<eblocks, 256, 0, stream>>>(h1, ssrc, sdst, W2, offs, agg, maxchunks);
  finalize2_pool<<<2048, 256, 0, stream>>>(agg, h1, Wl2, b2, n2g, pooled, cnt, N);
  classifier<<<(B + 127) / 128, 128, 0, stream>>>(pooled, cnt, Wc, bc, (float*)d_out, B);
}